// Round 3
// baseline (1354.337 us; speedup 1.0000x reference)
//
#include <hip/hip_runtime.h>
#include <hip/hip_bf16.h>

#define NN 4096
#define NI 16384   // N*I
#define HH 32

typedef __attribute__((ext_vector_type(8))) short short8;
typedef __attribute__((ext_vector_type(4))) float f32x4;

__device__ __forceinline__ short f2bs(float f) {
  __hip_bfloat16 b = __float2bfloat16(f);
  return *(short*)&b;
}

// Diagnostic: fill out with 0.5 first; pipeline must overwrite all of it.
__global__ void k_probe(float* __restrict__ out) {
  out[blockIdx.x * 256 + threadIdx.x] = 0.5f;
}

// ---------------- adj f32 -> bf16 (once per call; adj is constant) ----------------
__global__ void k_cvt(const float* __restrict__ a, short* __restrict__ ab) {
  const long i = ((long)blockIdx.x * 256 + threadIdx.x) * 8;
  const float4 v0 = *(const float4*)(a + i);
  const float4 v1 = *(const float4*)(a + i + 4);
  short8 r;
  r[0] = f2bs(v0.x); r[1] = f2bs(v0.y); r[2] = f2bs(v0.z); r[3] = f2bs(v0.w);
  r[4] = f2bs(v1.x); r[5] = f2bs(v1.y); r[6] = f2bs(v1.z); r[7] = f2bs(v1.w);
  *(short8*)(ab + i) = r;
}

// ---------------- natural cubic spline -> dX/dt at s=0, 0.5, 1 ----------------
__global__ void k_spline(const float* __restrict__ x,
                         float* __restrict__ dx0, float* __restrict__ dxh,
                         float* __restrict__ dx1) {
  const int c = blockIdx.x * 256 + threadIdx.x;  // channel 0..16383
  float y[16];
#pragma unroll
  for (int t = 0; t < 16; ++t) y[t] = x[t * NI + c];
  float cp[15], dp[15], M[16];
  cp[1] = 0.25f;
  dp[1] = (6.f * (y[2] - 2.f * y[1] + y[0])) * 0.25f;
#pragma unroll
  for (int i = 2; i <= 14; ++i) {
    float ri = 6.f * (y[i + 1] - 2.f * y[i] + y[i - 1]);
    float inv = 1.f / (4.f - cp[i - 1]);
    cp[i] = inv;
    dp[i] = (ri - dp[i - 1]) * inv;
  }
  M[0] = 0.f; M[15] = 0.f;
  M[14] = dp[14];
#pragma unroll
  for (int i = 13; i >= 1; --i) M[i] = dp[i] - cp[i] * M[i + 1];
#pragma unroll
  for (int i = 0; i < 15; ++i) {
    float b = (y[i + 1] - y[i]) - (2.f * M[i] + M[i + 1]) * (1.f / 6.f);
    float cc = 0.5f * M[i];
    float dd = (M[i + 1] - M[i]) * (1.f / 6.f);
    dx0[i * NI + c] = b;
    dxh[i * NI + c] = b + cc + 0.75f * dd;
    dx1[i * NI + c] = b + 2.f * cc + 3.f * dd;
  }
}

// ---------------- encoder: z0 = x[0] @ W_enc + b_enc ----------------
__global__ void k_enc(const float* __restrict__ x,
                      const float* __restrict__ We,
                      const float* __restrict__ be,
                      float* __restrict__ zcur, float* __restrict__ ze,
                      __hip_bfloat16* __restrict__ zT) {
  const int g = blockIdx.x * 256 + threadIdx.x;  // 0..131071
  const int n = g >> 5, h = g & 31;
  float acc = be[h];
#pragma unroll
  for (int i = 0; i < 4; ++i) acc = fmaf(x[n * 4 + i], We[i * 32 + h], acc);
  zcur[g] = acc;
  ze[g] = acc;
  zT[(long)h * NN + n] = __float2bfloat16(acc);
}

// ---------------- decoder for t=0 ----------------
__global__ void k_dec0(const float* __restrict__ z,
                       const float* __restrict__ W1,
                       const float* __restrict__ b1,
                       const float* __restrict__ W2,
                       const float* __restrict__ b2,
                       float* __restrict__ out) {
  __shared__ float W1s[32][17];
  __shared__ float b1s[16], W2s[16], b2s;
  const int tid = threadIdx.x;
  for (int idx = tid; idx < 512; idx += 256) W1s[idx >> 4][idx & 15] = W1[idx];
  if (tid < 16) { b1s[tid] = b1[tid]; W2s[tid] = W2[tid]; }
  if (tid == 0) b2s = b2[0];
  __syncthreads();
  const int n = blockIdx.x * 256 + tid;  // 0..4095
  const float* zr = z + (long)n * 32;
  float zv[32];
#pragma unroll
  for (int hh = 0; hh < 32; ++hh) zv[hh] = zr[hh];
  float acc = b2s;
#pragma unroll
  for (int jj = 0; jj < 16; ++jj) {
    float hv = b1s[jj];
#pragma unroll
    for (int hh = 0; hh < 32; ++hh) hv = fmaf(zv[hh], W1s[hh][jj], hv);
    acc = fmaf(fmaxf(hv, 0.f), W2s[jj], acc);
  }
  out[n] = 1.f / (1.f + expf(-acc));
}

// ---------------- one vector-field evaluation (MFMA matmul + fused epilogue) ----
// 256 threads = 4 waves; block owns 16 rows; wave w covers K in [w*1024, +1024).
// ADJ_BF16: adj pre-converted to bf16 in ws. Else: convert f32->bf16 in-register.
template <bool ADJ_BF16>
__global__ __launch_bounds__(256) void k_vf(
    const void* __restrict__ adjv,
    const __hip_bfloat16* __restrict__ zT_in,
    __hip_bfloat16* __restrict__ zT_out,
    float* __restrict__ z_eval,
    const float* __restrict__ z_base,
    float* __restrict__ z_next,
    float* __restrict__ kout,
    const float* __restrict__ k1, const float* __restrict__ k2,
    const float* __restrict__ k3,
    const float* __restrict__ dxsel,
    const float* __restrict__ Wg, const float* __restrict__ bg,
    const float* __restrict__ Wt, const float* __restrict__ bt,
    const float* __restrict__ Wp, const float* __restrict__ bp,
    const float* __restrict__ Wd1, const float* __restrict__ bd1,
    const float* __restrict__ Wd2, const float* __restrict__ bd2,
    float* __restrict__ out, int out_base, int j) {
  __shared__ float red[4][16][32];
  __shared__ float zn_s[16][32];       // zn; reused for final z when j==4
  __shared__ float h_s[16][32];
  __shared__ float ze_s[16][32];
  __shared__ float Wg_s[32][32];
  __shared__ float Wt_s[32][32];
  __shared__ float Wp_s[32][132];      // +4 pad
  __shared__ float Wd1_s[32][16];
  __shared__ float bgt_s[32];
  __shared__ float bp_s[128];
  __shared__ float dsm[33];            // b_d1[0:16], W_d2[16:32], b_d2[32]

  const int tid = threadIdx.x;
  const int lane = tid & 63;
  const int w = tid >> 6;          // 0..3
  const int r0 = blockIdx.x * 16;

  // stage small operands (visibility via the barrier after MFMA partials)
  for (int idx = tid; idx < 1024; idx += 256) {
    Wg_s[idx >> 5][idx & 31] = Wg[idx];
    Wt_s[idx >> 5][idx & 31] = Wt[idx];
  }
  for (int idx = tid; idx < 4096; idx += 256)
    Wp_s[idx >> 7][idx & 127] = Wp[idx];
  if (tid < 32) bgt_s[tid] = bg[tid] + bt[tid];
  if (tid < 128) bp_s[tid] = bp[tid];
  ze_s[tid >> 5][tid & 31] = z_eval[r0 * 32 + tid];
  {
    const int t2 = tid + 256;
    ze_s[t2 >> 5][t2 & 31] = z_eval[r0 * 32 + t2];
  }
  if (j == 4) {
    for (int idx = tid; idx < 512; idx += 256)
      Wd1_s[idx >> 4][idx & 15] = Wd1[idx];
    if (tid < 16) { dsm[tid] = bd1[tid]; dsm[16 + tid] = Wd2[tid]; }
    if (tid == 0) dsm[32] = bd2[0];
  }

  // ---- MFMA: zn = adj @ z, rows r0..r0+15 ----
  const short* ztp = (const short*)zT_in;
  const int frow = lane & 15;
  const int koct = (lane >> 4) * 8;
  f32x4 acc0 = {0.f, 0.f, 0.f, 0.f};
  f32x4 acc1 = {0.f, 0.f, 0.f, 0.f};
  const long arow = (long)(r0 + frow) * NN;
  const long brow0 = (long)frow * NN;
  const long brow1 = (long)(frow + 16) * NN;
  const int kbase = w * 1024 + koct;
#pragma unroll 8
  for (int it = 0; it < 32; ++it) {
    const int k = kbase + it * 32;
    short8 a;
    if constexpr (ADJ_BF16) {
      a = *(const short8*)((const short*)adjv + arow + k);
    } else {
      const float* af = (const float*)adjv + arow + k;
      const float4 u0 = *(const float4*)af;
      const float4 u1 = *(const float4*)(af + 4);
      a[0] = f2bs(u0.x); a[1] = f2bs(u0.y); a[2] = f2bs(u0.z); a[3] = f2bs(u0.w);
      a[4] = f2bs(u1.x); a[5] = f2bs(u1.y); a[6] = f2bs(u1.z); a[7] = f2bs(u1.w);
    }
    const short8 b0 = *(const short8*)(ztp + brow0 + k);
    const short8 b1 = *(const short8*)(ztp + brow1 + k);
    acc0 = __builtin_amdgcn_mfma_f32_16x16x32_bf16(a, b0, acc0, 0, 0, 0);
    acc1 = __builtin_amdgcn_mfma_f32_16x16x32_bf16(a, b1, acc1, 0, 0, 0);
  }
  {
    const int crow = (lane >> 4) * 4;   // C/D: col=lane&15, row=quad*4+reg
    const int ccol = lane & 15;
#pragma unroll
    for (int q = 0; q < 4; ++q) {
      red[w][crow + q][ccol] = acc0[q];
      red[w][crow + q][ccol + 16] = acc1[q];
    }
  }
  __syncthreads();

  // ---- cross-wave reduction (2 elements per thread) ----
#pragma unroll
  for (int e = 0; e < 2; ++e) {
    const int idx = tid + e * 256;
    const int r = idx >> 5, c = idx & 31;
    zn_s[r][c] = red[0][r][c] + red[1][r][c] + red[2][r][c] + red[3][r][c];
  }
  __syncthreads();

  // ---- h = relu(zn@Wg + ze@Wt + bg + bt) ----
#pragma unroll
  for (int e = 0; e < 2; ++e) {
    const int idx = tid + e * 256;
    const int r = idx >> 5, c = idx & 31;
    float hv = bgt_s[c];
#pragma unroll
    for (int kk = 0; kk < 32; ++kk)
      hv = fmaf(zn_s[r][kk], Wg_s[kk][c], fmaf(ze_s[r][kk], Wt_s[kk][c], hv));
    h_s[r][c] = fmaxf(hv, 0.f);
  }
  __syncthreads();

  // ---- k = einsum(sens, dxdt); RK4 update (block owns its rows) ----
#pragma unroll
  for (int e = 0; e < 2; ++e) {
    const int idx = tid + e * 256;
    const int r = idx >> 5, c = idx & 31;
    const long row = r0 + r;
    float kv = 0.f;
#pragma unroll
    for (int i = 0; i < 4; ++i) {
      float s = bp_s[c * 4 + i];
#pragma unroll
      for (int hp = 0; hp < 32; ++hp) s = fmaf(h_s[r][hp], Wp_s[hp][c * 4 + i], s);
      kv = fmaf(s, dxsel[row * 4 + i], kv);
    }
    const long g = row * 32 + c;
    float znew;
    if (j == 4) {
      znew = z_base[g] + (k1[g] + 2.f * k2[g] + 2.f * k3[g] + kv) * (1.f / 6.f);
      z_next[g] = znew;
      zn_s[r][c] = znew;  // final-z tile for the fused decode
    } else {
      kout[g] = kv;
      znew = z_base[g] + ((j == 3) ? 1.f : 0.5f) * kv;
    }
    z_eval[g] = znew;
    zT_out[(long)c * NN + row] = __float2bfloat16(znew);
  }

  // ---- fused decoder for z_{t+1} (j==4 only; uniform branch) ----
  if (j == 4) {
    __syncthreads();
    if (tid < 16) {
      float acc = dsm[32];
#pragma unroll
      for (int jj = 0; jj < 16; ++jj) {
        float hv = dsm[jj];
#pragma unroll
        for (int hh = 0; hh < 32; ++hh) hv = fmaf(zn_s[tid][hh], Wd1_s[hh][jj], hv);
        acc = fmaf(fmaxf(hv, 0.f), dsm[16 + jj], acc);
      }
      out[out_base + r0 + tid] = 1.f / (1.f + expf(-acc));
    }
  }
}

extern "C" void kernel_launch(void* const* d_in, const int* in_sizes, int n_in,
                              void* d_out, int out_size, void* d_ws, size_t ws_size,
                              hipStream_t stream) {
  (void)in_sizes; (void)n_in; (void)out_size;
  const float* x      = (const float*)d_in[0];
  const float* adj    = (const float*)d_in[1];
  const float* W_enc  = (const float*)d_in[2];
  const float* b_enc  = (const float*)d_in[3];
  const float* W_gcn  = (const float*)d_in[4];
  const float* b_gcn  = (const float*)d_in[5];
  const float* W_time = (const float*)d_in[6];
  const float* b_time = (const float*)d_in[7];
  const float* W_proj = (const float*)d_in[8];
  const float* b_proj = (const float*)d_in[9];
  const float* W_d1   = (const float*)d_in[10];
  const float* b_d1   = (const float*)d_in[11];
  const float* W_d2   = (const float*)d_in[12];
  const float* b_d2   = (const float*)d_in[13];
  float* out = (float*)d_out;

  // workspace carve: f32 arrays (6.1 MB) + zT ping/pong (0.5 MB) + optional adj_bf16 (33.6 MB)
  float* dx0   = (float*)d_ws;           // 15*16384
  float* dxh   = dx0 + 15 * NI;
  float* dx1   = dxh + 15 * NI;
  float* zcur  = dx1 + 15 * NI;          // (4096,32) f32
  float* znext = zcur + NN * HH;
  float* zev   = znext + NN * HH;
  float* k1b   = zev + NN * HH;
  float* k2b   = k1b + NN * HH;
  float* k3b   = k2b + NN * HH;
  __hip_bfloat16* zTa = (__hip_bfloat16*)(k3b + NN * HH);
  __hip_bfloat16* zTb = zTa + HH * NN;
  short* adjb = (short*)(zTb + HH * NN);
  const size_t need_bf16 = (size_t)((char*)(adjb + (long)NN * NN) - (char*)d_ws);
  const bool use_adjb = ws_size >= need_bf16;

  k_probe<<<256, 256, 0, stream>>>(out);
  if (use_adjb) k_cvt<<<8192, 256, 0, stream>>>(adj, adjb);
  k_spline<<<64, 256, 0, stream>>>(x, dx0, dxh, dx1);
  k_enc<<<512, 256, 0, stream>>>(x, W_enc, b_enc, zcur, zev, zTa);
  k_dec0<<<16, 256, 0, stream>>>(zcur, W_d1, b_d1, W_d2, b_d2, out);

  __hip_bfloat16* zin = zTa;
  __hip_bfloat16* zout = zTb;
  for (int t = 0; t < 15; ++t) {
    const float* ds[4] = { dx0 + t * NI, dxh + t * NI, dxh + t * NI, dx1 + t * NI };
    for (int j = 1; j <= 4; ++j) {
      float* ko = (j == 1) ? k1b : (j == 2) ? k2b : k3b;
      if (use_adjb)
        k_vf<true><<<256, 256, 0, stream>>>(adjb, zin, zout, zev, zcur, znext, ko,
                                            k1b, k2b, k3b, ds[j - 1],
                                            W_gcn, b_gcn, W_time, b_time, W_proj, b_proj,
                                            W_d1, b_d1, W_d2, b_d2, out, (t + 1) * NN, j);
      else
        k_vf<false><<<256, 256, 0, stream>>>(adj, zin, zout, zev, zcur, znext, ko,
                                             k1b, k2b, k3b, ds[j - 1],
                                             W_gcn, b_gcn, W_time, b_time, W_proj, b_proj,
                                             W_d1, b_d1, W_d2, b_d2, out, (t + 1) * NN, j);
      __hip_bfloat16* tmp = zin; zin = zout; zout = tmp;
    }
    float* tz = zcur; zcur = znext; znext = tz;
  }
}

// Round 4
// 810.374 us; speedup vs baseline: 1.6712x; 1.6712x over previous
//
#include <hip/hip_runtime.h>
#include <hip/hip_bf16.h>

#define NN 4096
#define NI 16384   // N*I
#define HH 32

typedef __attribute__((ext_vector_type(8))) short short8;
typedef __attribute__((ext_vector_type(4))) float f32x4;

__device__ __forceinline__ short f2bs(float f) {
  __hip_bfloat16 b = __float2bfloat16(f);
  return *(short*)&b;
}

// ---- adj f32 -> bf16, permuted into MFMA A-fragment order ----
// Fragment (R, W, i) = 64 lanes x 8 bf16, contiguous 1 KB:
//   element: adj[R*16 + (lane&15)][W*512 + i*32 + (lane>>4)*8 + j], j=0..7
// grid: 256 blocks (R), 512 threads (W = tid>>6, lane = tid&63).
__global__ __launch_bounds__(512) void k_cvt(const float* __restrict__ a,
                                             short* __restrict__ ab) {
  const int tid = threadIdx.x;
  const int W = tid >> 6, lane = tid & 63;
  const int fr = lane & 15, oct = lane >> 4;
  const int R = blockIdx.x;
  const float* srow = a + (long)(R * 16 + fr) * NN + W * 512 + oct * 8;
  short* drow = ab + ((long)(R * 8 + W) * 16) * 512 + lane * 8;
#pragma unroll 4
  for (int i = 0; i < 16; ++i) {
    const float4 u0 = *(const float4*)(srow + i * 32);
    const float4 u1 = *(const float4*)(srow + i * 32 + 4);
    short8 r;
    r[0] = f2bs(u0.x); r[1] = f2bs(u0.y); r[2] = f2bs(u0.z); r[3] = f2bs(u0.w);
    r[4] = f2bs(u1.x); r[5] = f2bs(u1.y); r[6] = f2bs(u1.z); r[7] = f2bs(u1.w);
    *(short8*)(drow + i * 512) = r;
  }
}

// zT B-fragment layout helper: element z[n][h] lives at short index
//   ((hb*128 + kb)*64 + hl + 16*oct)*8 + j
// where hb=h>>4, hl=h&15, kb=n>>5, oct=(n>>3)&3, j=n&7.
__device__ __forceinline__ long zt_idx(int n, int h) {
  const int hb = h >> 4, hl = h & 15;
  const int kb = n >> 5, oct = (n >> 3) & 3, j = n & 7;
  return ((long)(hb * 128 + kb) * 64 + hl + 16 * oct) * 8 + j;
}

// ---------------- natural cubic spline -> dX/dt at s=0, 0.5, 1 ----------------
__global__ void k_spline(const float* __restrict__ x,
                         float* __restrict__ dx0, float* __restrict__ dxh,
                         float* __restrict__ dx1) {
  const int c = blockIdx.x * 256 + threadIdx.x;  // channel 0..16383
  float y[16];
#pragma unroll
  for (int t = 0; t < 16; ++t) y[t] = x[t * NI + c];
  float cp[15], dp[15], M[16];
  cp[1] = 0.25f;
  dp[1] = (6.f * (y[2] - 2.f * y[1] + y[0])) * 0.25f;
#pragma unroll
  for (int i = 2; i <= 14; ++i) {
    float ri = 6.f * (y[i + 1] - 2.f * y[i] + y[i - 1]);
    float inv = 1.f / (4.f - cp[i - 1]);
    cp[i] = inv;
    dp[i] = (ri - dp[i - 1]) * inv;
  }
  M[0] = 0.f; M[15] = 0.f;
  M[14] = dp[14];
#pragma unroll
  for (int i = 13; i >= 1; --i) M[i] = dp[i] - cp[i] * M[i + 1];
#pragma unroll
  for (int i = 0; i < 15; ++i) {
    float b = (y[i + 1] - y[i]) - (2.f * M[i] + M[i + 1]) * (1.f / 6.f);
    float cc = 0.5f * M[i];
    float dd = (M[i + 1] - M[i]) * (1.f / 6.f);
    dx0[i * NI + c] = b;
    dxh[i * NI + c] = b + cc + 0.75f * dd;
    dx1[i * NI + c] = b + 2.f * cc + 3.f * dd;
  }
}

// ---------------- encoder: z0 = x[0] @ W_enc + b_enc ----------------
__global__ void k_enc(const float* __restrict__ x,
                      const float* __restrict__ We,
                      const float* __restrict__ be,
                      float* __restrict__ zcur, float* __restrict__ ze,
                      short* __restrict__ zT) {
  const int g = blockIdx.x * 256 + threadIdx.x;  // 0..131071
  const int n = g >> 5, h = g & 31;
  float acc = be[h];
#pragma unroll
  for (int i = 0; i < 4; ++i) acc = fmaf(x[n * 4 + i], We[i * 32 + h], acc);
  zcur[g] = acc;
  ze[g] = acc;
  zT[zt_idx(n, h)] = f2bs(acc);
}

// ---------------- decoder for t=0 ----------------
__global__ void k_dec0(const float* __restrict__ z,
                       const float* __restrict__ W1,
                       const float* __restrict__ b1,
                       const float* __restrict__ W2,
                       const float* __restrict__ b2,
                       float* __restrict__ out) {
  __shared__ float W1s[32][17];
  __shared__ float b1s[16], W2s[16], b2s;
  const int tid = threadIdx.x;
  for (int idx = tid; idx < 512; idx += 256) W1s[idx >> 4][idx & 15] = W1[idx];
  if (tid < 16) { b1s[tid] = b1[tid]; W2s[tid] = W2[tid]; }
  if (tid == 0) b2s = b2[0];
  __syncthreads();
  const int n = blockIdx.x * 256 + tid;  // 0..4095
  const float* zr = z + (long)n * 32;
  float zv[32];
#pragma unroll
  for (int hh = 0; hh < 32; ++hh) zv[hh] = zr[hh];
  float acc = b2s;
#pragma unroll
  for (int jj = 0; jj < 16; ++jj) {
    float hv = b1s[jj];
#pragma unroll
    for (int hh = 0; hh < 32; ++hh) hv = fmaf(zv[hh], W1s[hh][jj], hv);
    acc = fmaf(fmaxf(hv, 0.f), W2s[jj], acc);
  }
  out[n] = 1.f / (1.f + expf(-acc));
}

// ---------------- one vector-field evaluation (MFMA matmul + fused epilogue) ----
// 512 threads = 8 waves; block owns 16 rows; wave w covers K in [w*512, +512).
// adj and zT are both in MFMA-fragment order -> all loads lane-contiguous 16B.
__global__ __launch_bounds__(512) void k_vf(
    const short* __restrict__ adjb,
    const short* __restrict__ zT_in,
    short* __restrict__ zT_out,
    float* __restrict__ z_eval,
    const float* __restrict__ z_base,
    float* __restrict__ z_next,
    float* __restrict__ kout,
    const float* __restrict__ k1, const float* __restrict__ k2,
    const float* __restrict__ k3,
    const float* __restrict__ dxsel,
    const float* __restrict__ Wg, const float* __restrict__ bg,
    const float* __restrict__ Wt, const float* __restrict__ bt,
    const float* __restrict__ Wp, const float* __restrict__ bp,
    const float* __restrict__ Wd1, const float* __restrict__ bd1,
    const float* __restrict__ Wd2, const float* __restrict__ bd2,
    float* __restrict__ out, int out_base, int j) {
  __shared__ float red[8][16][32];     // 16 KB
  __shared__ float zn_s[16][32];       // zn; reused for final z when j==4
  __shared__ float h_s[16][32];
  __shared__ float ze_s[16][32];
  __shared__ float Wg_s[32][32];
  __shared__ float Wt_s[32][32];
  __shared__ float Wp_s[32][132];      // +4 pad
  __shared__ float Wd1_s[32][16];
  __shared__ float bgt_s[32];
  __shared__ float bp_s[128];
  __shared__ float dsm[33];            // b_d1[0:16], W_d2[16:32], b_d2[32]

  const int tid = threadIdx.x;
  const int lane = tid & 63;
  const int w = tid >> 6;          // 0..7
  const int r0 = blockIdx.x * 16;

  // stage small operands (visibility via the barrier after MFMA partials)
  for (int idx = tid; idx < 1024; idx += 512) {
    Wg_s[idx >> 5][idx & 31] = Wg[idx];
    Wt_s[idx >> 5][idx & 31] = Wt[idx];
  }
  for (int idx = tid; idx < 4096; idx += 512)
    Wp_s[idx >> 7][idx & 127] = Wp[idx];
  if (tid < 32) bgt_s[tid] = bg[tid] + bt[tid];
  if (tid < 128) bp_s[tid] = bp[tid];
  ze_s[tid >> 5][tid & 31] = z_eval[r0 * 32 + tid];
  if (j == 4) {
    Wd1_s[tid >> 4 & 31][tid & 15] = (tid < 512) ? Wd1[tid] : 0.f;  // tid<512 always
    if (tid < 16) { dsm[tid] = bd1[tid]; dsm[16 + tid] = Wd2[tid]; }
    if (tid == 0) dsm[32] = bd2[0];
  }

  // ---- MFMA: zn = adj @ z, rows r0..r0+15; all loads contiguous 16B/lane ----
  f32x4 acc0 = {0.f, 0.f, 0.f, 0.f};
  f32x4 acc1 = {0.f, 0.f, 0.f, 0.f};
  const short* ap = adjb + ((long)(blockIdx.x * 8 + w) * 16) * 512 + lane * 8;
  const short* b0p = zT_in + ((long)(w * 16)) * 512 + lane * 8;          // hb=0, kb=w*16+i
  const short* b1p = zT_in + ((long)(128 + w * 16)) * 512 + lane * 8;    // hb=1
#pragma unroll 8
  for (int i = 0; i < 16; ++i) {
    const short8 a  = *(const short8*)(ap + i * 512);
    const short8 b0 = *(const short8*)(b0p + i * 512);
    const short8 b1 = *(const short8*)(b1p + i * 512);
    acc0 = __builtin_amdgcn_mfma_f32_16x16x32_bf16(a, b0, acc0, 0, 0, 0);
    acc1 = __builtin_amdgcn_mfma_f32_16x16x32_bf16(a, b1, acc1, 0, 0, 0);
  }
  {
    const int crow = (lane >> 4) * 4;   // C/D: col=lane&15, row=quad*4+reg
    const int ccol = lane & 15;
#pragma unroll
    for (int q = 0; q < 4; ++q) {
      red[w][crow + q][ccol] = acc0[q];
      red[w][crow + q][ccol + 16] = acc1[q];
    }
  }
  __syncthreads();

  // ---- cross-wave reduction: thread (r,c) owns one zn element ----
  const int r = tid >> 5, c = tid & 31;
  {
    float zn = 0.f;
#pragma unroll
    for (int q = 0; q < 8; ++q) zn += red[q][r][c];
    zn_s[r][c] = zn;
  }
  __syncthreads();

  // ---- h = relu(zn@Wg + ze@Wt + bg + bt) ----
  {
    float hv = bgt_s[c];
#pragma unroll
    for (int kk = 0; kk < 32; ++kk)
      hv = fmaf(zn_s[r][kk], Wg_s[kk][c], fmaf(ze_s[r][kk], Wt_s[kk][c], hv));
    h_s[r][c] = fmaxf(hv, 0.f);
  }
  __syncthreads();

  // ---- k = einsum(sens, dxdt); RK4 update (block owns its rows) ----
  {
    const long row = r0 + r;
    float kv = 0.f;
#pragma unroll
    for (int i = 0; i < 4; ++i) {
      float s = bp_s[c * 4 + i];
#pragma unroll
      for (int hp = 0; hp < 32; ++hp) s = fmaf(h_s[r][hp], Wp_s[hp][c * 4 + i], s);
      kv = fmaf(s, dxsel[row * 4 + i], kv);
    }
    const long g = row * 32 + c;
    float znew;
    if (j == 4) {
      znew = z_base[g] + (k1[g] + 2.f * k2[g] + 2.f * k3[g] + kv) * (1.f / 6.f);
      z_next[g] = znew;
      zn_s[r][c] = znew;  // final-z tile for the fused decode
    } else {
      kout[g] = kv;
      znew = z_base[g] + ((j == 3) ? 1.f : 0.5f) * kv;
    }
    z_eval[g] = znew;
    zT_out[zt_idx((int)row, c)] = f2bs(znew);
  }

  // ---- fused decoder for z_{t+1} (j==4 only; uniform branch) ----
  if (j == 4) {
    __syncthreads();
    if (tid < 16) {
      float acc = dsm[32];
#pragma unroll
      for (int jj = 0; jj < 16; ++jj) {
        float hv = dsm[jj];
#pragma unroll
        for (int hh = 0; hh < 32; ++hh) hv = fmaf(zn_s[tid][hh], Wd1_s[hh][jj], hv);
        acc = fmaf(fmaxf(hv, 0.f), dsm[16 + jj], acc);
      }
      out[out_base + r0 + tid] = 1.f / (1.f + expf(-acc));
    }
  }
}

extern "C" void kernel_launch(void* const* d_in, const int* in_sizes, int n_in,
                              void* d_out, int out_size, void* d_ws, size_t ws_size,
                              hipStream_t stream) {
  (void)in_sizes; (void)n_in; (void)out_size; (void)ws_size;
  const float* x      = (const float*)d_in[0];
  const float* adj    = (const float*)d_in[1];
  const float* W_enc  = (const float*)d_in[2];
  const float* b_enc  = (const float*)d_in[3];
  const float* W_gcn  = (const float*)d_in[4];
  const float* b_gcn  = (const float*)d_in[5];
  const float* W_time = (const float*)d_in[6];
  const float* b_time = (const float*)d_in[7];
  const float* W_proj = (const float*)d_in[8];
  const float* b_proj = (const float*)d_in[9];
  const float* W_d1   = (const float*)d_in[10];
  const float* b_d1   = (const float*)d_in[11];
  const float* W_d2   = (const float*)d_in[12];
  const float* b_d2   = (const float*)d_in[13];
  float* out = (float*)d_out;

  // workspace carve (~40 MB; ws_size = 256 MiB per profile)
  float* dx0   = (float*)d_ws;           // 15*16384
  float* dxh   = dx0 + 15 * NI;
  float* dx1   = dxh + 15 * NI;
  float* zcur  = dx1 + 15 * NI;          // (4096,32) f32
  float* znext = zcur + NN * HH;
  float* zev   = znext + NN * HH;
  float* k1b   = zev + NN * HH;
  float* k2b   = k1b + NN * HH;
  float* k3b   = k2b + NN * HH;
  short* zTa   = (short*)(k3b + NN * HH);   // (32,4096) bf16 frag-order, ping
  short* zTb   = zTa + HH * NN;             // pong
  short* adjb  = zTb + HH * NN;             // (4096,4096) bf16 frag-order

  k_cvt<<<256, 512, 0, stream>>>(adj, adjb);
  k_spline<<<64, 256, 0, stream>>>(x, dx0, dxh, dx1);
  k_enc<<<512, 256, 0, stream>>>(x, W_enc, b_enc, zcur, zev, zTa);
  k_dec0<<<16, 256, 0, stream>>>(zcur, W_d1, b_d1, W_d2, b_d2, out);

  short* zin = zTa;
  short* zout = zTb;
  for (int t = 0; t < 15; ++t) {
    const float* ds[4] = { dx0 + t * NI, dxh + t * NI, dxh + t * NI, dx1 + t * NI };
    for (int j = 1; j <= 4; ++j) {
      float* ko = (j == 1) ? k1b : (j == 2) ? k2b : k3b;
      k_vf<<<256, 512, 0, stream>>>(adjb, zin, zout, zev, zcur, znext, ko,
                                    k1b, k2b, k3b, ds[j - 1],
                                    W_gcn, b_gcn, W_time, b_time, W_proj, b_proj,
                                    W_d1, b_d1, W_d2, b_d2, out, (t + 1) * NN, j);
      short* tmp = zin; zin = zout; zout = tmp;
    }
    float* tz = zcur; zcur = znext; znext = tz;
  }
}